// Round 8
// baseline (201.381 us; speedup 1.0000x reference)
//
#include <hip/hip_runtime.h>
#include <hip/hip_fp16.h>

// ChebyshevKAN: y[b,o] = sum_{i,j} U_j(tanh(x[b,i])) * C[i,o,j]
//   B=65536, I=512, O=32, degree 8 (j=0..8).
// Strategy: f16 MFMA GEMM [B x 4096] * [4096 x 32], A generated in registers.
//   - j=0 term (U_0 = 1) folded into bias[o] = sum_i C[i,o,0].
//   - K order: chunk ci (32 i's) x steps j=1..8; each K-32 step = one j.
//   - A-frag (16x16x32): A[m=lane&15][k=quad*8+e] -> lane owns 8 consecutive i
//     of its row; U recurrence advances j in fp32 registers. No LDS for A.
//   - B pre-swizzled to fragment order; staged to LDS (lgkmcnt-decoupled from
//     the x vmcnt stream — R5 showed direct-global B costs +17 us).
//   - R7 (kept): bias distributed over blocks 0..31 of the pack grid
//     (R6's single-straggler-block fusion cost +14 us; this one is free).
//   - R8: chunk-PAIR staging — 32 KB staged per barrier, 2 chunks computed
//     per iteration. Barriers drop 16 -> 8; each __syncthreads forces a
//     vmcnt(0) drain of the staging burst (~1000 cy, all waves stalled), so
//     halving their count should cut ~2.5-4 us. LDS 2x32 KB = 64 KB/block,
//     128 KB/CU at 2 blocks/CU (fits 160 KB).

typedef _Float16 half8 __attribute__((ext_vector_type(8)));
typedef float float4v __attribute__((ext_vector_type(4)));

#define N_ROWS   65536
#define N_I      512
#define N_O      32
#define N_CHUNKS 16          // 512 / 32
#define N_PAIRS  8           // chunks processed two at a time
#define STEPS    8           // j = 1..8
#define CHUNK_F16 8192       // 8 steps * 2 tiles * 64 lanes * 8 f16
#define PAIR_F16  16384      // two chunks

// ---- pack + distributed-bias kernel (512 blocks x 256 threads) ----
// All blocks: coeffs [512][32][9] fp32 -> B_sw fragment-ordered f16
//   B_sw flat index: ((s_glob*2 + t)*64 + L)*8 + jj
//   s_glob = ci*8 + (j-1); k_local(ii) = (L>>4)*8 + jj; i = ci*32 + ii
//   n(o) = t*16 + (L&15)
// Blocks 0..31: wave 0 additionally computes bias[o=blockIdx.x].
__global__ void pack_b_bias(const float* __restrict__ coeffs,
                            _Float16* __restrict__ bsw,
                            float* __restrict__ bias) {
    int id = blockIdx.x * 256 + threadIdx.x;
    {
        int jj = id & 7;
        int L  = (id >> 3) & 63;
        int t  = (id >> 9) & 1;
        int s  = id >> 10;                 // 0..127
        int ci = s >> 3, sl = s & 7;
        int j  = sl + 1;                   // 1..8
        int ii = ((L >> 4) << 3) + jj;
        int i  = ci * 32 + ii;
        int o  = t * 16 + (L & 15);
        bsw[id] = (_Float16)coeffs[(i * 32 + o) * 9 + j];
    }
    // distributed bias: block b < 32 handles column o = b with its wave 0
    if (blockIdx.x < 32 && threadIdx.x < 64) {
        int o = blockIdx.x;
        int t = threadIdx.x;
        float s = 0.f;
#pragma unroll
        for (int k = 0; k < 8; ++k) s += coeffs[((t + k * 64) * 32 + o) * 9 + 0];
        for (int off = 32; off; off >>= 1) s += __shfl_down(s, off, 64);
        if (t == 0) bias[o] = s;
    }
}

__device__ __forceinline__ float fast_tanh(float v) {
    // tanh(v) = 1 - 2/(exp(2v)+1); graceful at +-inf. ~2ulp, far below f16 quant.
    float e = __expf(2.0f * v);
    return __builtin_fmaf(-2.0f, __builtin_amdgcn_rcpf(e + 1.0f), 1.0f);
}

// ---- main kernel ----
// block = 256 thr = 4 waves; wave owns 32 rows (2 M-tiles) x 32 cols (2 N-tiles)
// grid = 512 blocks (2 blocks/CU)
__global__ __launch_bounds__(256, 2) void cheby_main(
        const float* __restrict__ x, const _Float16* __restrict__ bsw,
        const float* __restrict__ bias, float* __restrict__ y) {
    __shared__ __align__(16) _Float16 bl[2][PAIR_F16];    // 2 x 32KB B double-buffer

    const int tid = threadIdx.x;
    const int wv  = tid >> 6;
    const int L   = tid & 63;
    const int q   = L >> 4;       // quad 0..3
    const int mr  = L & 15;       // row-in-tile / col-in-tile
    const int m0  = blockIdx.x * 128 + wv * 32;
    const int r0  = m0 + mr;      // M-tile 0 row
    const int r1  = r0 + 16;      // M-tile 1 row

    // stage chunk-pair 0 into buffer 0 (all 256 threads, 8 x uint4 each)
    {
        const uint4* src = (const uint4*)bsw;             // pair 0 at offset 0
        uint4* dst = (uint4*)&bl[0][0];
#pragma unroll
        for (int it = 0; it < 8; ++it) dst[it * 256 + tid] = src[it * 256 + tid];
    }

    float4v acc[2][2];
#pragma unroll
    for (int a = 0; a < 2; ++a)
#pragma unroll
        for (int b = 0; b < 2; ++b)
#pragma unroll
            for (int e = 0; e < 4; ++e) acc[a][b][e] = 0.f;

    for (int cp = 0; cp < N_PAIRS; ++cp) {
        __syncthreads();                 // current pair staged & prev reads done
        const int buf = cp & 1;
        if (cp < N_PAIRS - 1) {          // prefetch next pair into other buffer
            const uint4* src = (const uint4*)(bsw + (size_t)(cp + 1) * PAIR_F16);
            uint4* dst = (uint4*)&bl[buf ^ 1][0];
#pragma unroll
            for (int it = 0; it < 8; ++it) dst[it * 256 + tid] = src[it * 256 + tid];
        }

#pragma unroll
        for (int sub = 0; sub < 2; ++sub) {
            const int ci = cp * 2 + sub;
            const _Float16* bc = &bl[buf][sub * CHUNK_F16];

            // lane's 8 i's for this chunk: i = ci*32 + q*8 + e
            const int i0 = ci * 32 + q * 8;
            const float4v xa = *(const float4v*)(x + (size_t)r0 * N_I + i0);
            const float4v xb = *(const float4v*)(x + (size_t)r0 * N_I + i0 + 4);
            const float4v xc = *(const float4v*)(x + (size_t)r1 * N_I + i0);
            const float4v xd = *(const float4v*)(x + (size_t)r1 * N_I + i0 + 4);

            float w0[8], w1[8], up0[8], uc0[8], up1[8], uc1[8];
#pragma unroll
            for (int e = 0; e < 4; ++e) {
                w0[e]     = 2.0f * fast_tanh(xa[e]);
                w0[e + 4] = 2.0f * fast_tanh(xb[e]);
                w1[e]     = 2.0f * fast_tanh(xc[e]);
                w1[e + 4] = 2.0f * fast_tanh(xd[e]);
            }
#pragma unroll
            for (int e = 0; e < 8; ++e) {    // U_0 = 1, U_1 = 2*xt
                up0[e] = 1.0f; uc0[e] = w0[e];
                up1[e] = 1.0f; uc1[e] = w1[e];
            }

#pragma unroll
            for (int s = 0; s < STEPS; ++s) {    // j = s+1
                half8 a0, a1;
#pragma unroll
                for (int e = 0; e < 8; ++e) {
                    a0[e] = (_Float16)uc0[e];
                    a1[e] = (_Float16)uc1[e];
                }
                const half8 b0 = *(const half8*)&bc[(s * 2 + 0) * 512 + L * 8];
                const half8 b1 = *(const half8*)&bc[(s * 2 + 1) * 512 + L * 8];
                acc[0][0] = __builtin_amdgcn_mfma_f32_16x16x32_f16(a0, b0, acc[0][0], 0, 0, 0);
                acc[0][1] = __builtin_amdgcn_mfma_f32_16x16x32_f16(a0, b1, acc[0][1], 0, 0, 0);
                acc[1][0] = __builtin_amdgcn_mfma_f32_16x16x32_f16(a1, b0, acc[1][0], 0, 0, 0);
                acc[1][1] = __builtin_amdgcn_mfma_f32_16x16x32_f16(a1, b1, acc[1][1], 0, 0, 0);
                // advance recurrence: U_{n+1} = 2*xt*U_n - U_{n-1}
#pragma unroll
                for (int e = 0; e < 8; ++e) {
                    float n0 = __builtin_fmaf(w0[e], uc0[e], -up0[e]);
                    float n1 = __builtin_fmaf(w1[e], uc1[e], -up1[e]);
                    up0[e] = uc0[e]; uc0[e] = n0;
                    up1[e] = uc1[e]; uc1[e] = n1;
                }
            }
        }
    }

    // epilogue: C/D layout row = q*4 + e, col = mr (verified 16x16 mapping)
    const float b_n0 = bias[mr];
    const float b_n1 = bias[16 + mr];
#pragma unroll
    for (int mt = 0; mt < 2; ++mt) {
#pragma unroll
        for (int e = 0; e < 4; ++e) {
            const int r = m0 + mt * 16 + q * 4 + e;
            y[(size_t)r * N_O + mr]      = acc[mt][0][e] + b_n0;
            y[(size_t)r * N_O + 16 + mr] = acc[mt][1][e] + b_n1;
        }
    }
}

extern "C" void kernel_launch(void* const* d_in, const int* in_sizes, int n_in,
                              void* d_out, int out_size, void* d_ws, size_t ws_size,
                              hipStream_t stream) {
    const float* x      = (const float*)d_in[0];
    const float* coeffs = (const float*)d_in[1];
    float* yout = (float*)d_out;

    _Float16* bsw = (_Float16*)d_ws;                               // 131072 f16 = 256KB
    float* bias   = (float*)((char*)d_ws + 131072 * sizeof(_Float16));

    pack_b_bias<<<512, 256, 0, stream>>>(coeffs, bsw, bias);
    cheby_main<<<512, 256, 0, stream>>>(x, bsw, bias, yout);
}

// Round 9
// 196.484 us; speedup vs baseline: 1.0249x; 1.0249x over previous
//
#include <hip/hip_runtime.h>
#include <hip/hip_fp16.h>

// ChebyshevKAN: y[b,o] = sum_{i,j} U_j(tanh(x[b,i])) * C[i,o,j]
//   B=65536, I=512, O=32, degree 8 (j=0..8).
// Strategy: f16 MFMA GEMM [B x 4096] * [4096 x 32], A generated in registers.
//   - j=0 term (U_0 = 1) folded into bias[o] = sum_i C[i,o,0].
//   - K order: chunk ci (32 i's) x steps j=1..8; each K-32 step = one j.
//   - A-frag (16x16x32): A[m=lane&15][k=quad*8+e] -> lane owns 8 consecutive i
//     of its row; U recurrence advances j in fp32 registers. No LDS for A.
//   - B pre-swizzled to fragment order; 16KB/chunk double-buffered in LDS.
//     LDS keeps B on lgkmcnt, decoupled from the x vmcnt stream (R5: global B
//     loads serialize MFMA steps on the vmcnt FIFO, +17 us).
//   - cheby_main BIT-IDENTICAL to R0 (the empirical optimum; R2/R4/R5/R8
//     perturbations all neutral-or-negative).
//   - bias distributed over blocks 0..31 of the pack grid (R7, -3.3 us;
//     R6's single-straggler-block variant cost +14 us).
//   - R9: VERBATIM REVERT to the best measured kernel (R7, 196.7 us).
//     R8's chunk-pair staging (+4.7 us) showed the staging drain is
//     per-byte-conserved, not per-barrier — no further structural room.

typedef _Float16 half8 __attribute__((ext_vector_type(8)));
typedef float float4v __attribute__((ext_vector_type(4)));

#define N_ROWS   65536
#define N_I      512
#define N_O      32
#define N_CHUNKS 16          // 512 / 32
#define STEPS    8           // j = 1..8
#define CHUNK_F16 8192       // 8 steps * 2 tiles * 64 lanes * 8 f16

// ---- pack + distributed-bias kernel (512 blocks x 256 threads) ----
// All blocks: coeffs [512][32][9] fp32 -> B_sw fragment-ordered f16
//   B_sw flat index: ((s_glob*2 + t)*64 + L)*8 + jj
//   s_glob = ci*8 + (j-1); k_local(ii) = (L>>4)*8 + jj; i = ci*32 + ii
//   n(o) = t*16 + (L&15)
// Blocks 0..31: wave 0 additionally computes bias[o=blockIdx.x]
//   (8 scattered loads/thread, spread over 32 CUs, concurrent with pack).
__global__ void pack_b_bias(const float* __restrict__ coeffs,
                            _Float16* __restrict__ bsw,
                            float* __restrict__ bias) {
    int id = blockIdx.x * 256 + threadIdx.x;
    {
        int jj = id & 7;
        int L  = (id >> 3) & 63;
        int t  = (id >> 9) & 1;
        int s  = id >> 10;                 // 0..127
        int ci = s >> 3, sl = s & 7;
        int j  = sl + 1;                   // 1..8
        int ii = ((L >> 4) << 3) + jj;
        int i  = ci * 32 + ii;
        int o  = t * 16 + (L & 15);
        bsw[id] = (_Float16)coeffs[(i * 32 + o) * 9 + j];
    }
    // distributed bias: block b < 32 handles column o = b with its wave 0
    if (blockIdx.x < 32 && threadIdx.x < 64) {
        int o = blockIdx.x;
        int t = threadIdx.x;
        float s = 0.f;
#pragma unroll
        for (int k = 0; k < 8; ++k) s += coeffs[((t + k * 64) * 32 + o) * 9 + 0];
        for (int off = 32; off; off >>= 1) s += __shfl_down(s, off, 64);
        if (t == 0) bias[o] = s;
    }
}

__device__ __forceinline__ float fast_tanh(float v) {
    // tanh(v) = 1 - 2/(exp(2v)+1); graceful at +-inf. ~2ulp, far below f16 quant.
    float e = __expf(2.0f * v);
    return __builtin_fmaf(-2.0f, __builtin_amdgcn_rcpf(e + 1.0f), 1.0f);
}

// ---- main kernel (verbatim R0 — the empirical optimum) ----
// block = 256 thr = 4 waves; wave owns 32 rows (2 M-tiles) x 32 cols (2 N-tiles)
// grid = 512 blocks (2 blocks/CU)
__global__ __launch_bounds__(256, 2) void cheby_main(
        const float* __restrict__ x, const _Float16* __restrict__ bsw,
        const float* __restrict__ bias, float* __restrict__ y) {
    __shared__ __align__(16) _Float16 bl[2][CHUNK_F16];   // 2 x 16KB B double-buffer

    const int tid = threadIdx.x;
    const int wv  = tid >> 6;
    const int L   = tid & 63;
    const int q   = L >> 4;       // quad 0..3
    const int mr  = L & 15;       // row-in-tile / col-in-tile
    const int m0  = blockIdx.x * 128 + wv * 32;
    const int r0  = m0 + mr;      // M-tile 0 row
    const int r1  = r0 + 16;      // M-tile 1 row

    // stage chunk 0 into buffer 0 (all 256 threads)
    {
        const uint4* src = (const uint4*)bsw;             // chunk0 at offset 0
        uint4* dst = (uint4*)&bl[0][0];
#pragma unroll
        for (int it = 0; it < 4; ++it) dst[it * 256 + tid] = src[it * 256 + tid];
    }

    float4v acc[2][2];
#pragma unroll
    for (int a = 0; a < 2; ++a)
#pragma unroll
        for (int b = 0; b < 2; ++b)
#pragma unroll
            for (int e = 0; e < 4; ++e) acc[a][b][e] = 0.f;

    for (int ci = 0; ci < N_CHUNKS; ++ci) {
        __syncthreads();                 // current buffer staged & prev reads done
        const int buf = ci & 1;
        if (ci < N_CHUNKS - 1) {         // prefetch next B chunk into other buffer
            const uint4* src = (const uint4*)(bsw + (ci + 1) * CHUNK_F16);
            uint4* dst = (uint4*)&bl[buf ^ 1][0];
#pragma unroll
            for (int it = 0; it < 4; ++it) dst[it * 256 + tid] = src[it * 256 + tid];
        }

        // lane's 8 i's for this chunk: i = ci*32 + q*8 + e
        const int i0 = ci * 32 + q * 8;
        const float4v xa = *(const float4v*)(x + (size_t)r0 * N_I + i0);
        const float4v xb = *(const float4v*)(x + (size_t)r0 * N_I + i0 + 4);
        const float4v xc = *(const float4v*)(x + (size_t)r1 * N_I + i0);
        const float4v xd = *(const float4v*)(x + (size_t)r1 * N_I + i0 + 4);

        float w0[8], w1[8], up0[8], uc0[8], up1[8], uc1[8];
#pragma unroll
        for (int e = 0; e < 4; ++e) {
            w0[e]     = 2.0f * fast_tanh(xa[e]);
            w0[e + 4] = 2.0f * fast_tanh(xb[e]);
            w1[e]     = 2.0f * fast_tanh(xc[e]);
            w1[e + 4] = 2.0f * fast_tanh(xd[e]);
        }
#pragma unroll
        for (int e = 0; e < 8; ++e) {    // U_0 = 1, U_1 = 2*xt
            up0[e] = 1.0f; uc0[e] = w0[e];
            up1[e] = 1.0f; uc1[e] = w1[e];
        }

#pragma unroll
        for (int s = 0; s < STEPS; ++s) {    // j = s+1
            half8 a0, a1;
#pragma unroll
            for (int e = 0; e < 8; ++e) {
                a0[e] = (_Float16)uc0[e];
                a1[e] = (_Float16)uc1[e];
            }
            const half8 b0 = *(const half8*)&bl[buf][(s * 2 + 0) * 512 + L * 8];
            const half8 b1 = *(const half8*)&bl[buf][(s * 2 + 1) * 512 + L * 8];
            acc[0][0] = __builtin_amdgcn_mfma_f32_16x16x32_f16(a0, b0, acc[0][0], 0, 0, 0);
            acc[0][1] = __builtin_amdgcn_mfma_f32_16x16x32_f16(a0, b1, acc[0][1], 0, 0, 0);
            acc[1][0] = __builtin_amdgcn_mfma_f32_16x16x32_f16(a1, b0, acc[1][0], 0, 0, 0);
            acc[1][1] = __builtin_amdgcn_mfma_f32_16x16x32_f16(a1, b1, acc[1][1], 0, 0, 0);
            // advance recurrence: U_{n+1} = 2*xt*U_n - U_{n-1}
#pragma unroll
            for (int e = 0; e < 8; ++e) {
                float n0 = __builtin_fmaf(w0[e], uc0[e], -up0[e]);
                float n1 = __builtin_fmaf(w1[e], uc1[e], -up1[e]);
                up0[e] = uc0[e]; uc0[e] = n0;
                up1[e] = uc1[e]; uc1[e] = n1;
            }
        }
    }

    // epilogue: C/D layout row = q*4 + e, col = mr (verified 16x16 mapping)
    const float b_n0 = bias[mr];
    const float b_n1 = bias[16 + mr];
#pragma unroll
    for (int mt = 0; mt < 2; ++mt) {
#pragma unroll
        for (int e = 0; e < 4; ++e) {
            const int r = m0 + mt * 16 + q * 4 + e;
            y[(size_t)r * N_O + mr]      = acc[mt][0][e] + b_n0;
            y[(size_t)r * N_O + 16 + mr] = acc[mt][1][e] + b_n1;
        }
    }
}

extern "C" void kernel_launch(void* const* d_in, const int* in_sizes, int n_in,
                              void* d_out, int out_size, void* d_ws, size_t ws_size,
                              hipStream_t stream) {
    const float* x      = (const float*)d_in[0];
    const float* coeffs = (const float*)d_in[1];
    float* yout = (float*)d_out;

    _Float16* bsw = (_Float16*)d_ws;                               // 131072 f16 = 256KB
    float* bias   = (float*)((char*)d_ws + 131072 * sizeof(_Float16));

    pack_b_bias<<<512, 256, 0, stream>>>(coeffs, bsw, bias);
    cheby_main<<<512, 256, 0, stream>>>(x, bsw, bias, yout);
}